// Round 13
// baseline (1446.949 us; speedup 1.0000x reference)
//
#include <hip/hip_runtime.h>
#include <stdint.h>

#define BATCH 16
#define NPTS  4096
#define NSAMP 1024

typedef __attribute__((ext_vector_type(8))) short  short8;
typedef __attribute__((ext_vector_type(4))) float  floatx4;

__device__ __forceinline__ unsigned short f2bf(float f) {
    unsigned u = __float_as_uint(f);
    unsigned r = (u + 0x7FFFu + ((u >> 16) & 1u)) >> 16;
    return (unsigned short)r;
}

// u64 max with DPP source (VALU-latency path, no ds ops).
// CTRL 0x121/2/4/8 = row_ror:1/2/4/8 ; 0x142 = row_bcast15 ; 0x143 = row_bcast31
template<int CTRL>
__device__ __forceinline__ uint64_t dpp_max_u64(uint64_t k) {
    int lo = (int)(unsigned)k;
    int hi = (int)(unsigned)(k >> 32);
    int lo2 = __builtin_amdgcn_update_dpp(0, lo, CTRL, 0xF, 0xF, false);
    int hi2 = __builtin_amdgcn_update_dpp(0, hi, CTRL, 0xF, 0xF, false);
    uint64_t o = ((uint64_t)(unsigned)hi2 << 32) | (unsigned)lo2;
    return o > k ? o : k;  // non-receiving lanes get 0 -> never win (keys > 0)
}

#define WT_S 18432   // shorts per scale in wtab

// ---------------------------------------------------------------------------
// FPS (+fused feat->bf16 conversion + wtab conversion on extra blocks).
// FPS local-best: f32 tree on (dist, slot) — f32 order == uint order for
// nonneg values; keep-left tie-break == smallest index. One u64 key packed
// at the end; DPP reduce / argmax tie-break identical to the u64-tree.
// FPS is at ~94% of its serial-chain floor — frozen.
// Blocks [16, 16+1024*staged): feat f32->bf16. Last 108 blocks: wtab.
// ---------------------------------------------------------------------------
__global__ __launch_bounds__(512) void fps_conv_kernel(
    const float* __restrict__ xyz,            // [B,N,3] f32
    float* __restrict__ out_xyz,              // d_out head [B,S,3] f32
    const float* __restrict__ feat,           // [B,N,64] f32
    unsigned short* __restrict__ featb,       // staged bf16 table (or null)
    int staged,
    const float* __restrict__ w0, const float* __restrict__ w1,
    const float* __restrict__ w2, unsigned short* __restrict__ wtab)
{
#pragma clang fp contract(off)
    const int wbase = 16 + (staged ? 1024 : 0);
    if (blockIdx.x >= (unsigned)wbase) {      // ---- wtab conversion part ----
        int t = (blockIdx.x - wbase) * 512 + threadIdx.x;  // 108*512 = 55296
        if (t < 3*WT_S) {
            int s = t / WT_S, r = t % WT_S;
            unsigned short v = 0;
            if (r < 6144) {                   // w0b: n = r/96, kg = r%96
                int n = r / 96, kg = r % 96;
                if (kg < 67) {
                    int ci = (kg < 64) ? (kg + 3) : (kg - 64);
                    v = f2bf(w0[(size_t)(s*64 + n)*67 + ci]);
                }
            } else if (r < 10240) {           // w1b
                int idx = r - 6144;
                v = f2bf(w1[(size_t)(s*64 + (idx >> 6))*64 + (idx & 63)]);
            } else {                          // w2b
                int idx = r - 10240;
                v = f2bf(w2[(size_t)(s*128 + (idx >> 6))*64 + (idx & 63)]);
            }
            wtab[t] = v;
        }
        return;
    }
    if (blockIdx.x >= 16) {                   // ---- fused conv_feat part ----
        int t = (blockIdx.x - 16) * 512 + threadIdx.x;  // 8 elems each
        const float4* fp = (const float4*)feat + (size_t)t*2;
        float4 a = fp[0], c = fp[1];
        uint4 o;
        o.x = (unsigned)f2bf(a.x) | ((unsigned)f2bf(a.y) << 16);
        o.y = (unsigned)f2bf(a.z) | ((unsigned)f2bf(a.w) << 16);
        o.z = (unsigned)f2bf(c.x) | ((unsigned)f2bf(c.y) << 16);
        o.w = (unsigned)f2bf(c.z) | ((unsigned)f2bf(c.w) << 16);
        ((uint4*)featb)[t] = o;
        return;
    }

    const int b    = blockIdx.x;
    const int tid  = threadIdx.x;
    const int lane = tid & 63;
    const int wave = tid >> 6;                // 0..7
    const float* xb = xyz + (size_t)b * NPTS * 3;

    __shared__ float xsh[NPTS], ysh[NPTS], zsh[NPTS];   // 48 KB
    __shared__ float cents[NSAMP * 3];                  // 12 KB
    __shared__ uint64_t keylds[2][8];                   // 128 B

    float px[8], py[8], pz[8], dist[8];
#pragma unroll
    for (int i = 0; i < 8; ++i) {
        int p = tid + (i << 9);
        px[i] = xb[p*3+0];
        py[i] = xb[p*3+1];
        pz[i] = xb[p*3+2];
        dist[i] = 1e10f;
        xsh[p] = px[i]; ysh[p] = py[i]; zsh[p] = pz[i];
    }
    __syncthreads();

    float cx = xb[0], cy = xb[1], cz = xb[2];

    for (int it = 0; it < NSAMP; ++it) {
        if (tid == 0) {                       // LDS only — no vmcnt traffic
            cents[it*3+0] = cx; cents[it*3+1] = cy; cents[it*3+2] = cz;
        }
        if (it == NSAMP - 1) break;

        // ---- update this thread's 8 points ----
#pragma unroll
        for (int i = 0; i < 8; ++i) {
            float dx = px[i] - cx, dy = py[i] - cy, dz = pz[i] - cz;
            float d = dx*dx; d = d + dy*dy; d = d + dz*dz;
            dist[i] = fminf(dist[i], d);
        }
        // ---- f32 argmax tree, keep-left on ties (= smallest slot) ----
        float w01 = dist[1] > dist[0] ? dist[1] : dist[0];
        int   e01 = dist[1] > dist[0] ? 1 : 0;
        float w23 = dist[3] > dist[2] ? dist[3] : dist[2];
        int   e23 = dist[3] > dist[2] ? 3 : 2;
        float w45 = dist[5] > dist[4] ? dist[5] : dist[4];
        int   e45 = dist[5] > dist[4] ? 5 : 4;
        float w67 = dist[7] > dist[6] ? dist[7] : dist[6];
        int   e67 = dist[7] > dist[6] ? 7 : 6;
        float wa  = w23 > w01 ? w23 : w01;
        int   ea  = w23 > w01 ? e23 : e01;
        float wb  = w67 > w45 ? w67 : w45;
        int   eb  = w67 > w45 ? e67 : e45;
        float wv  = wb > wa ? wb : wa;
        int   wi  = wb > wa ? eb : ea;
        unsigned widx = (unsigned)(tid + (wi << 9));
        uint64_t kk = ((uint64_t)__float_as_uint(wv) << 32) | (~widx);

        // ---- wave reduce: 4 row_ror (row all-reduce) + 2 row_bcast ----
        kk = dpp_max_u64<0x121>(kk);   // row_ror:1
        kk = dpp_max_u64<0x122>(kk);   // row_ror:2
        kk = dpp_max_u64<0x124>(kk);   // row_ror:4
        kk = dpp_max_u64<0x128>(kk);   // row_ror:8  -> each row all-reduced
        kk = dpp_max_u64<0x142>(kk);   // row_bcast15: row r gets row r-1
        kk = dpp_max_u64<0x143>(kk);   // row_bcast31: lanes 48-63 = wave max

        // ---- one key per wave through LDS (double-buffered slot) ----
        int pb = it & 1;
        if (lane == 63) keylds[pb][wave] = kk;
        __syncthreads();                      // only lgkm pending — cheap

        // ---- lane-parallel final 8 -> 1 (period-8 pattern, 3 DPP) ----
        uint64_t f = keylds[pb][lane & 7];
        f = dpp_max_u64<0x121>(f);
        f = dpp_max_u64<0x122>(f);
        f = dpp_max_u64<0x124>(f);            // all lanes: global winner
        int cur = (int)~((unsigned)f);

        cx = xsh[cur]; cy = ysh[cur]; cz = zsh[cur];
    }

    __syncthreads();
    for (int i = tid; i < NSAMP*3; i += 512)  // coalesced bulk store
        out_xyz[(size_t)b*NSAMP*3 + i] = cents[i];
}

// ---------------------------------------------------------------------------
// KNN: 1024 threads, 16 queries (waves) per block; LDS 56KB -> 2 blocks/CU
// -> 32 waves/CU (max). Per-wave filter-then-merge top-64 on packed u64
// (key<<32|idx) — exact lax.top_k semantics.
// ---------------------------------------------------------------------------
__global__ __launch_bounds__(1024) void knn_kernel(
    const float* __restrict__ xyz,
    const float* __restrict__ new_xyz,        // Output 0 (f32)
    unsigned short* __restrict__ knn_idx)     // [B*S, 64]
{
#pragma clang fp contract(off)
    __shared__ float xs[NPTS], ys[NPTS], zs[NPTS];      // 48 KB
    __shared__ uint64_t buf[16][64];                    //  8 KB
    const int tid  = threadIdx.x;
    const int lane = tid & 63;
    const int wave = tid >> 6;                // 0..15
    const int q = blockIdx.x * 16 + wave;     // 1024 % 16 == 0: no straddle
    const int b = q >> 10;
    const float* xb = xyz + (size_t)b * NPTS * 3;

    for (int i = tid; i < NPTS; i += 1024) {
        xs[i] = xb[i*3+0];
        ys[i] = xb[i*3+1];
        zs[i] = xb[i*3+2];
    }
    __syncthreads();

    const float qx = new_xyz[q*3+0], qy = new_xyz[q*3+1], qz = new_xyz[q*3+2];
    float aa = qx*qx; aa = aa + qy*qy; aa = aa + qz*qz;

    auto keyof = [&](int c) -> unsigned {
        float x = xs[c], y = ys[c], z = zs[c];
        float bb = x*x;  bb = bb + y*y;   bb = bb + z*z;
        float dt = qx*x; dt = dt + qy*y;  dt = dt + qz*z;
        float d2 = (aa + bb) - 2.0f*dt;
        unsigned u = __float_as_uint(d2);
        return (u & 0x80000000u) ? ~u : (u | 0x80000000u);
    };
    auto shfl64 = [&](uint64_t v, int src) -> uint64_t {
        int lo = __shfl((int)(unsigned)v, src);
        int hi = __shfl((int)(unsigned)(v >> 32), src);
        return ((uint64_t)(unsigned)hi << 32) | (unsigned)lo;
    };
    auto shflx64 = [&](uint64_t v, int m) -> uint64_t {
        int lo = __shfl_xor((int)(unsigned)v, m);
        int hi = __shfl_xor((int)(unsigned)(v >> 32), m);
        return ((uint64_t)(unsigned)hi << 32) | (unsigned)lo;
    };
    auto sortP = [&](uint64_t &p) {        // ascending bitonic sort across 64
#pragma unroll
        for (int kk = 2; kk <= 64; kk <<= 1) {
#pragma unroll
            for (int j = kk >> 1; j >= 1; j >>= 1) {
                uint64_t o = shflx64(p, j);
                bool up    = ((lane & kk) == 0);
                bool lower = ((lane & j) == 0);
                bool oless = o < p;
                bool keep  = (up == lower) ? oless : !oless;
                if (keep) p = o;
            }
        }
    };
    auto mergeP = [&](uint64_t &P, uint64_t Bv) {  // both asc; keep 64 smallest
        uint64_t rev = shfl64(Bv, 63 - lane);
        if (rev < P) P = rev;                      // bitonic now
#pragma unroll
        for (int j = 32; j >= 1; j >>= 1) {
            uint64_t o = shflx64(P, j);
            bool lower = ((lane & j) == 0);
            bool oless = o < P;
            bool keep  = lower ? oless : !oless;
            if (keep) P = o;
        }
    };

    uint64_t P = ((uint64_t)keyof(lane) << 32) | (unsigned)lane;
    sortP(P);
    uint64_t Pmax = shfl64(P, 63);
    int cnt = 0;                                   // wave-uniform buffer fill

    for (int bt = 1; bt < 64; ++bt) {
        int c = (bt << 6) + lane;
        uint64_t cand = ((uint64_t)keyof(c) << 32) | (unsigned)c;
        bool qual = cand < Pmax;
        unsigned long long mask = __ballot(qual);
        if (mask == 0ull) continue;
        int n = __popcll(mask);
        if (cnt + n > 64) {                        // flush buffer
            uint64_t Bv = (lane < cnt) ? buf[wave][lane] : ~0ull;
            sortP(Bv);
            mergeP(P, Bv);
            Pmax = shfl64(P, 63);
            cnt = 0;
            qual = qual && (cand < Pmax);          // re-qualify (tightened)
            mask = __ballot(qual);
            n = __popcll(mask);
        }
        if (qual) {
            int pos = cnt + __popcll(mask & ((1ull << lane) - 1ull));
            buf[wave][pos] = cand;
        }
        cnt += n;
    }
    if (cnt > 0) {
        uint64_t Bv = (lane < cnt) ? buf[wave][lane] : ~0ull;
        sortP(Bv);
        mergeP(P, Bv);
    }
    knn_idx[(size_t)q*64 + lane] = (unsigned short)(P & 0xFFFFu);
}

// ---------------------------------------------------------------------------
// MLP phases — r9/r12 structure + T14 reg-staged prefetch, LDS-NEUTRAL:
// single g_lds (25.6KB total, occupancy preserved — r10's double-buffer
// regressed on LDS-driven occupancy loss, NOT pipelining). Group g+1's
// gather loads issue into registers BEFORE group g's compute; the ds_write
// lands after the barrier ending g's reads. 2 barriers/group unchanged.
// ---------------------------------------------------------------------------
#define GPB 8   // groups per block

template<int PHASE>
__global__ __launch_bounds__(256) void mlp_phase(
    const float* __restrict__ xyz,
    const float* __restrict__ feat,
    const float* __restrict__ new_xyz,    // Output 0 (f32)
    const unsigned short* __restrict__ knn,
    const unsigned short* __restrict__ featb,  // staged bf16 feats (or null)
    int staged,
    const unsigned short* __restrict__ wtab,   // bf16 weight tables
    const float* __restrict__ bnp,        // [3][3][128][2] (s,t)
    float* __restrict__ stats,            // [3][3][128][2] (sum,sumsq)
    float* __restrict__ out1)             // fused region [B*S, 384] f32
{
    __shared__ __align__(16) unsigned short g_lds[64*104];
    __shared__ __align__(16) unsigned short a_lds[64*72];
    __shared__ float stat_lds[256];
    __shared__ float wavemax[4*128];

    const int tid  = threadIdx.x;
    const int lane = tid & 63;
    const int wave = tid >> 6;
    const int n16  = lane & 15;
    const int quad = lane >> 4;
    const int gr_r   = tid >> 2;          // gather row 0..63
    const int gr_sub = tid & 3;           // gather column quarter

    // ---- XCD-locality swizzle: bid -> (scale, g0) with batch = 2*xcd + hi.
    // Assumes round-robin bid->XCD (bid&7); bijective over 3584 blocks.
    int scale, g0;
    {
        int xcd = blockIdx.x & 7;
        int r   = blockIdx.x >> 3;        // 0..447
        int hi  = (r >= 224) ? 1 : 0;
        int bt  = 2*xcd + hi;             // batch 0..15
        int r2  = r - hi*224;             // 0..223
        if (r2 < 32)       { scale = 0; g0 = bt*256  + r2*GPB; }
        else if (r2 < 96)  { scale = 1; g0 = bt*512  + (r2-32)*GPB; }
        else               { scale = 2; g0 = bt*1024 + (r2-96)*GPB; }
    }
    const int KNB = 16 << scale;
    const int cpg = 4 >> scale;           // centroids per 64-row group
    const int wpc = 1 << scale;           // waves per centroid

    const unsigned short* wt  = wtab + scale * WT_S;
    const unsigned short* w2b = wt + 6144;    // [64][64]
    const unsigned short* w3b = wt + 10240;   // [128][64]

    // ---- resident L1 W fragments: 12 x 16B loads ----
    short8 w1f[4][3];
#pragma unroll
    for (int nt = 0; nt < 4; ++nt)
#pragma unroll
        for (int kb = 0; kb < 3; ++kb)
            w1f[nt][kb] = *(const short8*)&wt[(nt*16 + n16)*96 + kb*32 + quad*8];

    float s1p[4], t1p[4], s2p[4], t2p[4];
    if constexpr (PHASE >= 2) {
#pragma unroll
        for (int nt = 0; nt < 4; ++nt) {
            int o = ((0*3 + scale)*128 + nt*16 + n16)*2;
            s1p[nt] = bnp[o]; t1p[nt] = bnp[o+1];
        }
    }
    if constexpr (PHASE >= 3) {
#pragma unroll
        for (int nt = 0; nt < 4; ++nt) {
            int o = ((1*3 + scale)*128 + nt*16 + n16)*2;
            s2p[nt] = bnp[o]; t2p[nt] = bnp[o+1];
        }
    }

    float sac[8], sqac[8];
#pragma unroll
    for (int i = 0; i < 8; ++i) { sac[i] = 0.f; sqac[i] = 0.f; }
    stat_lds[tid] = 0.f;
    // hoisted zero-pad of g cols 72..95 (gather writes only cols 0..71)
    {
        if (gr_sub == 0)      *(uint4*)&g_lds[gr_r*104 + 72] = make_uint4(0u,0u,0u,0u);
        else if (gr_sub == 1) *(uint4*)&g_lds[gr_r*104 + 80] = make_uint4(0u,0u,0u,0u);
        else if (gr_sub == 2) *(uint4*)&g_lds[gr_r*104 + 88] = make_uint4(0u,0u,0u,0u);
    }

    // ---- staged gather: LOAD into regs (issue early) / WRITE late ----
    auto stage_load = [&](int gq, uint4& c0, uint4& c1, uint4& z) {
        const int cb2 = gq * cpg;
        const int ci  = cb2 + (gr_r >> (4 + scale));
        const int j   = gr_r & (KNB - 1);
        const int n   = knn[(size_t)ci*64 + j];
        const int b   = ci >> 10;
        if (staged) {
            const unsigned short* frow = featb + ((size_t)(b*NPTS + n))*64 + gr_sub*16;
            c0 = ((const uint4*)frow)[0];
            c1 = ((const uint4*)frow)[1];
        } else {
            const float* frow = feat + ((size_t)(b*NPTS + n))*64 + gr_sub*16;
            unsigned short h[16];
#pragma unroll
            for (int u = 0; u < 16; ++u) h[u] = f2bf(frow[u]);
            c0.x = (unsigned)h[0]  | ((unsigned)h[1]  << 16);
            c0.y = (unsigned)h[2]  | ((unsigned)h[3]  << 16);
            c0.z = (unsigned)h[4]  | ((unsigned)h[5]  << 16);
            c0.w = (unsigned)h[6]  | ((unsigned)h[7]  << 16);
            c1.x = (unsigned)h[8]  | ((unsigned)h[9]  << 16);
            c1.y = (unsigned)h[10] | ((unsigned)h[11] << 16);
            c1.z = (unsigned)h[12] | ((unsigned)h[13] << 16);
            c1.w = (unsigned)h[14] | ((unsigned)h[15] << 16);
        }
        if (gr_sub == 0) {
            const float* nx = new_xyz + (size_t)ci*3;
            const float* xp = xyz + ((size_t)(b*NPTS + n))*3;
            unsigned short h0 = f2bf(xp[0] - nx[0]);
            unsigned short h1 = f2bf(xp[1] - nx[1]);
            unsigned short h2 = f2bf(xp[2] - nx[2]);
            z = make_uint4((unsigned)h0 | ((unsigned)h1 << 16),
                           (unsigned)h2, 0u, 0u);
        }
    };
    auto stage_write = [&](const uint4& c0, const uint4& c1, const uint4& z) {
        *(uint4*)&g_lds[gr_r*104 + gr_sub*16]     = c0;
        *(uint4*)&g_lds[gr_r*104 + gr_sub*16 + 8] = c1;
        if (gr_sub == 0) *(uint4*)&g_lds[gr_r*104 + 64] = z;
    };

    // prologue: gather group g0
    uint4 sc0, sc1, sz;
    stage_load(g0, sc0, sc1, sz);
    stage_write(sc0, sc1, sz);
    __syncthreads();

    for (int g = g0; g < g0 + GPB; ++g) {
        const int cb   = g * cpg;
        const bool more = (g + 1 < g0 + GPB);
        if (more) stage_load(g + 1, sc0, sc1, sz);   // loads in flight

        // ---- L1 ----
        const int rb = wave*16 + n16;  // A-row for this lane
        short8 a0 = *(const short8*)&g_lds[rb*104 +      quad*8];
        short8 a1 = *(const short8*)&g_lds[rb*104 + 32 + quad*8];
        short8 a2 = *(const short8*)&g_lds[rb*104 + 64 + quad*8];
        floatx4 acc[4];
#pragma unroll
        for (int nt = 0; nt < 4; ++nt) {
            floatx4 c = {0.f,0.f,0.f,0.f};
            c = __builtin_amdgcn_mfma_f32_16x16x32_bf16(a0, w1f[nt][0], c, 0,0,0);
            c = __builtin_amdgcn_mfma_f32_16x16x32_bf16(a1, w1f[nt][1], c, 0,0,0);
            c = __builtin_amdgcn_mfma_f32_16x16x32_bf16(a2, w1f[nt][2], c, 0,0,0);
            acc[nt] = c;
        }

        if constexpr (PHASE == 1) {
#pragma unroll
            for (int nt = 0; nt < 4; ++nt) {
                floatx4 c = acc[nt];
                sac[nt]  += c[0]+c[1]+c[2]+c[3];
                sqac[nt] += c[0]*c[0]+c[1]*c[1]+c[2]*c[2]+c[3]*c[3];
            }
        }
        if constexpr (PHASE >= 2) {
            // a1 = relu(affine(x1)) -> LDS transpose (wave-private slab)
#pragma unroll
            for (int nt = 0; nt < 4; ++nt) {
                int ch = nt*16 + n16;
#pragma unroll
                for (int r = 0; r < 4; ++r) {
                    float v = acc[nt][r]*s1p[nt] + t1p[nt];
                    v = fmaxf(v, 0.f);
                    a_lds[(wave*16 + quad*4 + r)*72 + ch] = f2bf(v);
                }
            }
            short8 e0 = *(const short8*)&a_lds[rb*72 +      quad*8];
            short8 e1 = *(const short8*)&a_lds[rb*72 + 32 + quad*8];
            floatx4 acc2[4];
#pragma unroll
            for (int nt = 0; nt < 4; ++nt) {
                short8 wa = *(const short8*)&w2b[(nt*16 + n16)*64 +      quad*8];
                short8 wb = *(const short8*)&w2b[(nt*16 + n16)*64 + 32 + quad*8];
                floatx4 c = {0.f,0.f,0.f,0.f};
                c = __builtin_amdgcn_mfma_f32_16x16x32_bf16(e0, wa, c, 0,0,0);
                c = __builtin_amdgcn_mfma_f32_16x16x32_bf16(e1, wb, c, 0,0,0);
                acc2[nt] = c;
            }
            if constexpr (PHASE == 2) {
#pragma unroll
                for (int nt = 0; nt < 4; ++nt) {
                    floatx4 c = acc2[nt];
                    sac[nt]  += c[0]+c[1]+c[2]+c[3];
                    sqac[nt] += c[0]*c[0]+c[1]*c[1]+c[2]*c[2]+c[3]*c[3];
                }
            }
            if constexpr (PHASE == 3) {
#pragma unroll
                for (int nt = 0; nt < 4; ++nt) {
                    int ch = nt*16 + n16;
#pragma unroll
                    for (int r = 0; r < 4; ++r) {
                        float v = acc2[nt][r]*s2p[nt] + t2p[nt];
                        v = fmaxf(v, 0.f);
                        a_lds[(wave*16 + quad*4 + r)*72 + ch] = f2bf(v);
                    }
                }
                short8 f0 = *(const short8*)&a_lds[rb*72 +      quad*8];
                short8 f1 = *(const short8*)&a_lds[rb*72 + 32 + quad*8];
#pragma unroll
                for (int nt = 0; nt < 8; ++nt) {
                    short8 wa = *(const short8*)&w3b[(nt*16 + n16)*64 +      quad*8];
                    short8 wb = *(const short8*)&w3b[(nt*16 + n16)*64 + 32 + quad*8];
                    floatx4 c = {0.f,0.f,0.f,0.f};
                    c = __builtin_amdgcn_mfma_f32_16x16x32_bf16(f0, wa, c, 0,0,0);
                    c = __builtin_amdgcn_mfma_f32_16x16x32_bf16(f1, wb, c, 0,0,0);
                    sac[nt]  += c[0]+c[1]+c[2]+c[3];
                    sqac[nt] += c[0]*c[0]+c[1]*c[1]+c[2]*c[2]+c[3]*c[3];
                    float m = fmaxf(fmaxf(c[0],c[1]), fmaxf(c[2],c[3]));
                    m = fmaxf(m, __shfl_xor(m, 16));
                    m = fmaxf(m, __shfl_xor(m, 32));
                    if (lane < 16) wavemax[wave*128 + nt*16 + n16] = m;
                }
            }
        }
        __syncthreads();   // all reads of g_lds done; wavemax published

        if (more) stage_write(sc0, sc1, sz);  // write next tile (disjoint
                                              // from wavemax; epilogue safe)
        if constexpr (PHASE == 3) {
            const int ch = tid & 127;
            for (int ic = tid >> 7; ic < cpg; ic += 2) {
                float m = wavemax[(ic*wpc)*128 + ch];
                for (int w = 1; w < wpc; ++w)
                    m = fmaxf(m, wavemax[(ic*wpc + w)*128 + ch]);
                // raw (pre-BN3) max, f32, directly in the final output slot
                out1[(size_t)(cb + ic)*384 + scale*128 + ch] = m;
            }
        }
        __syncthreads();   // stage_write visible; epilogue reads done before
                           // next group's wavemax writes
    }

    // ---- flush stats ----
    const int NCH = (PHASE == 3) ? 8 : 4;
#pragma unroll
    for (int nt = 0; nt < 8; ++nt) {
        if (nt >= NCH) break;
        float v  = sac[nt], v2 = sqac[nt];
        v  += __shfl_xor(v, 16);  v  += __shfl_xor(v, 32);
        v2 += __shfl_xor(v2, 16); v2 += __shfl_xor(v2, 32);
        if (lane < 16) {
            int ch = nt*16 + n16;
            atomicAdd(&stat_lds[ch*2],   v);
            atomicAdd(&stat_lds[ch*2+1], v2);
        }
    }
    __syncthreads();
    const int layer = PHASE - 1;
    const int nch = (PHASE == 3) ? 128 : 64;
    if (tid < nch*2) {
        atomicAdd(&stats[(size_t)(layer*3 + scale)*256 + tid], stat_lds[tid]);
    }
}

// ---------------------------------------------------------------------------
__global__ void bn_params_kernel(
    const float* __restrict__ stats, float* __restrict__ bnp,
    const float* __restrict__ gamma, const float* __restrict__ beta,
    int layer, int nch)
{
    int t = blockIdx.x * blockDim.x + threadIdx.x;
    if (t >= 3*nch) return;
    int scale = t / nch, ch = t % nch;
    float M = 16384.0f * (float)(16 << scale);
    int o = ((layer*3 + scale)*128 + ch)*2;
    float sum = stats[o], sumsq = stats[o+1];
    float mean = sum / M;
    float var = sumsq / M - mean*mean;
    var = fmaxf(var, 0.f);
    float ga = gamma[scale*nch + ch];
    float be = beta[scale*nch + ch];
    float s  = ga / sqrtf(var + 1e-5f);
    float tt = be - mean * s;
    bnp[o] = s; bnp[o+1] = tt;
}

// In-place elementwise BN3+ReLU over the fused output region (f32, float4).
// 4-aligned channel groups never straddle the scale boundary (128%4==0).
__global__ void finalize_kernel(
    const float* __restrict__ bnp,
    float* __restrict__ out1)   // [B*S, 384] f32, holds raw maxima
{
    int t = blockIdx.x * 256 + threadIdx.x;    // 1,572,864 float4 groups
    float4 m = ((const float4*)out1)[t];
    int c0 = (t*4) % 384;
    int scale = c0 >> 7;
    int ch = c0 & 127;
    int o = ((2*3 + scale)*128 + ch)*2;
    float4 r;
    r.x = fmaxf(m.x*bnp[o+0] + bnp[o+1], 0.f);
    r.y = fmaxf(m.y*bnp[o+2] + bnp[o+3], 0.f);
    r.z = fmaxf(m.z*bnp[o+4] + bnp[o+5], 0.f);
    r.w = fmaxf(m.w*bnp[o+6] + bnp[o+7], 0.f);
    ((float4*)out1)[t] = r;
}

// ---------------------------------------------------------------------------
extern "C" void kernel_launch(void* const* d_in, const int* in_sizes, int n_in,
                              void* d_out, int out_size, void* d_ws, size_t ws_size,
                              hipStream_t stream)
{
    (void)in_sizes; (void)n_in; (void)out_size;
    const float* xyz  = (const float*)d_in[0];
    const float* feat = (const float*)d_in[1];
    const float* w0   = (const float*)d_in[2];
    const float* w1   = (const float*)d_in[3];
    const float* w2   = (const float*)d_in[4];
    const float* g0   = (const float*)d_in[5];
    const float* g1   = (const float*)d_in[6];
    const float* g2   = (const float*)d_in[7];
    const float* b0   = (const float*)d_in[8];
    const float* b1   = (const float*)d_in[9];
    const float* b2   = (const float*)d_in[10];
    float* out  = (float*)d_out;
    float* out0 = out;                 // [B,S,3]
    float* out1 = out + 49152;         // fused [B*S,384]

    // ws layouts:
    //  staged:   knn 2MB | featb 8MB | stats 9216 | bnp 9216 | wtab 110592
    //  fallback: knn 2MB | stats 9216 | bnp 9216 | wtab 110592
    char* ws = (char*)d_ws;
    const size_t NEED_FULL = 2097152ull + 8388608ull + 9216 + 9216 + 110592;
    const int staged = (ws_size >= NEED_FULL) ? 1 : 0;
    unsigned short* knn   = (unsigned short*)ws;
    unsigned short* featb = staged ? (unsigned short*)(ws + 2097152) : nullptr;
    size_t tail = staged ? (2097152ull + 8388608ull) : 2097152ull;
    float* stats = (float*)(ws + tail);
    float* bnp   = (float*)(ws + tail + 9216);
    unsigned short* wtab = (unsigned short*)(ws + tail + 18432);

    hipMemsetAsync(stats, 0, 9216, stream);
    // fps (blocks 0-15) + feat->bf16 (1024 blocks, staged) + wtab (108 blocks)
    fps_conv_kernel<<<16 + (staged ? 1024 : 0) + 108, 512, 0, stream>>>(
        xyz, out0, feat, featb, staged, w0, w1, w2, wtab);
    knn_kernel<<<1024, 1024, 0, stream>>>(xyz, out0, knn);

    mlp_phase<1><<<3584,256,0,stream>>>(xyz,feat,out0,knn,featb,staged,wtab,bnp,stats,out1);
    bn_params_kernel<<<1,256,0,stream>>>(stats, bnp, g0, b0, 0, 64);

    mlp_phase<2><<<3584,256,0,stream>>>(xyz,feat,out0,knn,featb,staged,wtab,bnp,stats,out1);
    bn_params_kernel<<<1,256,0,stream>>>(stats, bnp, g1, b1, 1, 64);

    mlp_phase<3><<<3584,256,0,stream>>>(xyz,feat,out0,knn,featb,staged,wtab,bnp,stats,out1);
    bn_params_kernel<<<2,256,0,stream>>>(stats, bnp, g2, b2, 2, 128);

    finalize_kernel<<<6144, 256, 0, stream>>>(bnp, out1);
}

// Round 14
// 1298.292 us; speedup vs baseline: 1.1145x; 1.1145x over previous
//
#include <hip/hip_runtime.h>
#include <stdint.h>

#define BATCH 16
#define NPTS  4096
#define NSAMP 1024

typedef __attribute__((ext_vector_type(8))) short  short8;
typedef __attribute__((ext_vector_type(4))) float  floatx4;

__device__ __forceinline__ unsigned short f2bf(float f) {
    unsigned u = __float_as_uint(f);
    unsigned r = (u + 0x7FFFu + ((u >> 16) & 1u)) >> 16;
    return (unsigned short)r;
}

// u64 max with DPP source (VALU-latency path, no ds ops).
// CTRL 0x121/2/4/8 = row_ror:1/2/4/8 ; 0x142 = row_bcast15 ; 0x143 = row_bcast31
template<int CTRL>
__device__ __forceinline__ uint64_t dpp_max_u64(uint64_t k) {
    int lo = (int)(unsigned)k;
    int hi = (int)(unsigned)(k >> 32);
    int lo2 = __builtin_amdgcn_update_dpp(0, lo, CTRL, 0xF, 0xF, false);
    int hi2 = __builtin_amdgcn_update_dpp(0, hi, CTRL, 0xF, 0xF, false);
    uint64_t o = ((uint64_t)(unsigned)hi2 << 32) | (unsigned)lo2;
    return o > k ? o : k;  // non-receiving lanes get 0 -> never win (keys > 0)
}

#define WT_S 18432   // shorts per scale in wtab

// ---------------------------------------------------------------------------
// FPS (+fused feat->bf16 conversion + wtab conversion on extra blocks).
// FPS local-best: f32 tree on (dist, slot) — f32 order == uint order for
// nonneg values; keep-left tie-break == smallest index. One u64 key packed
// at the end; DPP reduce / argmax tie-break identical to the u64-tree.
// FPS is at ~94% of its serial-chain floor — frozen.
// Blocks [16, 16+1024*staged): feat f32->bf16. Last 108 blocks: wtab.
// ---------------------------------------------------------------------------
__global__ __launch_bounds__(512) void fps_conv_kernel(
    const float* __restrict__ xyz,            // [B,N,3] f32
    float* __restrict__ out_xyz,              // d_out head [B,S,3] f32
    const float* __restrict__ feat,           // [B,N,64] f32
    unsigned short* __restrict__ featb,       // staged bf16 table (or null)
    int staged,
    const float* __restrict__ w0, const float* __restrict__ w1,
    const float* __restrict__ w2, unsigned short* __restrict__ wtab)
{
#pragma clang fp contract(off)
    const int wbase = 16 + (staged ? 1024 : 0);
    if (blockIdx.x >= (unsigned)wbase) {      // ---- wtab conversion part ----
        int t = (blockIdx.x - wbase) * 512 + threadIdx.x;  // 108*512 = 55296
        if (t < 3*WT_S) {
            int s = t / WT_S, r = t % WT_S;
            unsigned short v = 0;
            if (r < 6144) {                   // w0b: n = r/96, kg = r%96
                int n = r / 96, kg = r % 96;
                if (kg < 67) {
                    int ci = (kg < 64) ? (kg + 3) : (kg - 64);
                    v = f2bf(w0[(size_t)(s*64 + n)*67 + ci]);
                }
            } else if (r < 10240) {           // w1b
                int idx = r - 6144;
                v = f2bf(w1[(size_t)(s*64 + (idx >> 6))*64 + (idx & 63)]);
            } else {                          // w2b
                int idx = r - 10240;
                v = f2bf(w2[(size_t)(s*128 + (idx >> 6))*64 + (idx & 63)]);
            }
            wtab[t] = v;
        }
        return;
    }
    if (blockIdx.x >= 16) {                   // ---- fused conv_feat part ----
        int t = (blockIdx.x - 16) * 512 + threadIdx.x;  // 8 elems each
        const float4* fp = (const float4*)feat + (size_t)t*2;
        float4 a = fp[0], c = fp[1];
        uint4 o;
        o.x = (unsigned)f2bf(a.x) | ((unsigned)f2bf(a.y) << 16);
        o.y = (unsigned)f2bf(a.z) | ((unsigned)f2bf(a.w) << 16);
        o.z = (unsigned)f2bf(c.x) | ((unsigned)f2bf(c.y) << 16);
        o.w = (unsigned)f2bf(c.z) | ((unsigned)f2bf(c.w) << 16);
        ((uint4*)featb)[t] = o;
        return;
    }

    const int b    = blockIdx.x;
    const int tid  = threadIdx.x;
    const int lane = tid & 63;
    const int wave = tid >> 6;                // 0..7
    const float* xb = xyz + (size_t)b * NPTS * 3;

    __shared__ float xsh[NPTS], ysh[NPTS], zsh[NPTS];   // 48 KB
    __shared__ float cents[NSAMP * 3];                  // 12 KB
    __shared__ uint64_t keylds[2][8];                   // 128 B

    float px[8], py[8], pz[8], dist[8];
#pragma unroll
    for (int i = 0; i < 8; ++i) {
        int p = tid + (i << 9);
        px[i] = xb[p*3+0];
        py[i] = xb[p*3+1];
        pz[i] = xb[p*3+2];
        dist[i] = 1e10f;
        xsh[p] = px[i]; ysh[p] = py[i]; zsh[p] = pz[i];
    }
    __syncthreads();

    float cx = xb[0], cy = xb[1], cz = xb[2];

    for (int it = 0; it < NSAMP; ++it) {
        if (tid == 0) {                       // LDS only — no vmcnt traffic
            cents[it*3+0] = cx; cents[it*3+1] = cy; cents[it*3+2] = cz;
        }
        if (it == NSAMP - 1) break;

        // ---- update this thread's 8 points ----
#pragma unroll
        for (int i = 0; i < 8; ++i) {
            float dx = px[i] - cx, dy = py[i] - cy, dz = pz[i] - cz;
            float d = dx*dx; d = d + dy*dy; d = d + dz*dz;
            dist[i] = fminf(dist[i], d);
        }
        // ---- f32 argmax tree, keep-left on ties (= smallest slot) ----
        float w01 = dist[1] > dist[0] ? dist[1] : dist[0];
        int   e01 = dist[1] > dist[0] ? 1 : 0;
        float w23 = dist[3] > dist[2] ? dist[3] : dist[2];
        int   e23 = dist[3] > dist[2] ? 3 : 2;
        float w45 = dist[5] > dist[4] ? dist[5] : dist[4];
        int   e45 = dist[5] > dist[4] ? 5 : 4;
        float w67 = dist[7] > dist[6] ? dist[7] : dist[6];
        int   e67 = dist[7] > dist[6] ? 7 : 6;
        float wa  = w23 > w01 ? w23 : w01;
        int   ea  = w23 > w01 ? e23 : e01;
        float wb  = w67 > w45 ? w67 : w45;
        int   eb  = w67 > w45 ? e67 : e45;
        float wv  = wb > wa ? wb : wa;
        int   wi  = wb > wa ? eb : ea;
        unsigned widx = (unsigned)(tid + (wi << 9));
        uint64_t kk = ((uint64_t)__float_as_uint(wv) << 32) | (~widx);

        // ---- wave reduce: 4 row_ror (row all-reduce) + 2 row_bcast ----
        kk = dpp_max_u64<0x121>(kk);   // row_ror:1
        kk = dpp_max_u64<0x122>(kk);   // row_ror:2
        kk = dpp_max_u64<0x124>(kk);   // row_ror:4
        kk = dpp_max_u64<0x128>(kk);   // row_ror:8  -> each row all-reduced
        kk = dpp_max_u64<0x142>(kk);   // row_bcast15: row r gets row r-1
        kk = dpp_max_u64<0x143>(kk);   // row_bcast31: lanes 48-63 = wave max

        // ---- one key per wave through LDS (double-buffered slot) ----
        int pb = it & 1;
        if (lane == 63) keylds[pb][wave] = kk;
        __syncthreads();                      // only lgkm pending — cheap

        // ---- lane-parallel final 8 -> 1 (period-8 pattern, 3 DPP) ----
        uint64_t f = keylds[pb][lane & 7];
        f = dpp_max_u64<0x121>(f);
        f = dpp_max_u64<0x122>(f);
        f = dpp_max_u64<0x124>(f);            // all lanes: global winner
        int cur = (int)~((unsigned)f);

        cx = xsh[cur]; cy = ysh[cur]; cz = zsh[cur];
    }

    __syncthreads();
    for (int i = tid; i < NSAMP*3; i += 512)  // coalesced bulk store
        out_xyz[(size_t)b*NSAMP*3 + i] = cents[i];
}

// ---------------------------------------------------------------------------
// KNN: 1024 threads, 16 queries (waves) per block; LDS 56KB -> 2 blocks/CU
// -> 32 waves/CU (max). Per-wave filter-then-merge top-64 on packed u64
// (key<<32|idx) — exact lax.top_k semantics.
// ---------------------------------------------------------------------------
__global__ __launch_bounds__(1024) void knn_kernel(
    const float* __restrict__ xyz,
    const float* __restrict__ new_xyz,        // Output 0 (f32)
    unsigned short* __restrict__ knn_idx)     // [B*S, 64]
{
#pragma clang fp contract(off)
    __shared__ float xs[NPTS], ys[NPTS], zs[NPTS];      // 48 KB
    __shared__ uint64_t buf[16][64];                    //  8 KB
    const int tid  = threadIdx.x;
    const int lane = tid & 63;
    const int wave = tid >> 6;                // 0..15
    const int q = blockIdx.x * 16 + wave;     // 1024 % 16 == 0: no straddle
    const int b = q >> 10;
    const float* xb = xyz + (size_t)b * NPTS * 3;

    for (int i = tid; i < NPTS; i += 1024) {
        xs[i] = xb[i*3+0];
        ys[i] = xb[i*3+1];
        zs[i] = xb[i*3+2];
    }
    __syncthreads();

    const float qx = new_xyz[q*3+0], qy = new_xyz[q*3+1], qz = new_xyz[q*3+2];
    float aa = qx*qx; aa = aa + qy*qy; aa = aa + qz*qz;

    auto keyof = [&](int c) -> unsigned {
        float x = xs[c], y = ys[c], z = zs[c];
        float bb = x*x;  bb = bb + y*y;   bb = bb + z*z;
        float dt = qx*x; dt = dt + qy*y;  dt = dt + qz*z;
        float d2 = (aa + bb) - 2.0f*dt;
        unsigned u = __float_as_uint(d2);
        return (u & 0x80000000u) ? ~u : (u | 0x80000000u);
    };
    auto shfl64 = [&](uint64_t v, int src) -> uint64_t {
        int lo = __shfl((int)(unsigned)v, src);
        int hi = __shfl((int)(unsigned)(v >> 32), src);
        return ((uint64_t)(unsigned)hi << 32) | (unsigned)lo;
    };
    auto shflx64 = [&](uint64_t v, int m) -> uint64_t {
        int lo = __shfl_xor((int)(unsigned)v, m);
        int hi = __shfl_xor((int)(unsigned)(v >> 32), m);
        return ((uint64_t)(unsigned)hi << 32) | (unsigned)lo;
    };
    auto sortP = [&](uint64_t &p) {        // ascending bitonic sort across 64
#pragma unroll
        for (int kk = 2; kk <= 64; kk <<= 1) {
#pragma unroll
            for (int j = kk >> 1; j >= 1; j >>= 1) {
                uint64_t o = shflx64(p, j);
                bool up    = ((lane & kk) == 0);
                bool lower = ((lane & j) == 0);
                bool oless = o < p;
                bool keep  = (up == lower) ? oless : !oless;
                if (keep) p = o;
            }
        }
    };
    auto mergeP = [&](uint64_t &P, uint64_t Bv) {  // both asc; keep 64 smallest
        uint64_t rev = shfl64(Bv, 63 - lane);
        if (rev < P) P = rev;                      // bitonic now
#pragma unroll
        for (int j = 32; j >= 1; j >>= 1) {
            uint64_t o = shflx64(P, j);
            bool lower = ((lane & j) == 0);
            bool oless = o < P;
            bool keep  = lower ? oless : !oless;
            if (keep) P = o;
        }
    };

    uint64_t P = ((uint64_t)keyof(lane) << 32) | (unsigned)lane;
    sortP(P);
    uint64_t Pmax = shfl64(P, 63);
    int cnt = 0;                                   // wave-uniform buffer fill

    for (int bt = 1; bt < 64; ++bt) {
        int c = (bt << 6) + lane;
        uint64_t cand = ((uint64_t)keyof(c) << 32) | (unsigned)c;
        bool qual = cand < Pmax;
        unsigned long long mask = __ballot(qual);
        if (mask == 0ull) continue;
        int n = __popcll(mask);
        if (cnt + n > 64) {                        // flush buffer
            uint64_t Bv = (lane < cnt) ? buf[wave][lane] : ~0ull;
            sortP(Bv);
            mergeP(P, Bv);
            Pmax = shfl64(P, 63);
            cnt = 0;
            qual = qual && (cand < Pmax);          // re-qualify (tightened)
            mask = __ballot(qual);
            n = __popcll(mask);
        }
        if (qual) {
            int pos = cnt + __popcll(mask & ((1ull << lane) - 1ull));
            buf[wave][pos] = cand;
        }
        cnt += n;
    }
    if (cnt > 0) {
        uint64_t Bv = (lane < cnt) ? buf[wave][lane] : ~0ull;
        sortP(Bv);
        mergeP(P, Bv);
    }
    knn_idx[(size_t)q*64 + lane] = (unsigned short)(P & 0xFFFFu);
}

// ---------------------------------------------------------------------------
// MLP phases — r9 structure EXACTLY (verified 1298us in r12): XCD-locality
// swizzle, weight tables (resident w1f only), 2 barriers/group. r8
// (task-split), r10 (LDS double-buffer) and r13 (reg-staged prefetch) all
// regressed: at 16-24 waves/CU, TLP already hides the gather latency; every
// pipelining variant pays more in occupancy/serialization than it recovers.
// This layout is the confirmed local optimum.
// ---------------------------------------------------------------------------
#define GPB 8   // groups per block

template<int PHASE>
__global__ __launch_bounds__(256) void mlp_phase(
    const float* __restrict__ xyz,
    const float* __restrict__ feat,
    const float* __restrict__ new_xyz,    // Output 0 (f32)
    const unsigned short* __restrict__ knn,
    const unsigned short* __restrict__ featb,  // staged bf16 feats (or null)
    int staged,
    const unsigned short* __restrict__ wtab,   // bf16 weight tables
    const float* __restrict__ bnp,        // [3][3][128][2] (s,t)
    float* __restrict__ stats,            // [3][3][128][2] (sum,sumsq)
    float* __restrict__ out1)             // fused region [B*S, 384] f32
{
    __shared__ __align__(16) unsigned short g_lds[64*104];
    __shared__ __align__(16) unsigned short a_lds[64*72];
    __shared__ float stat_lds[256];
    __shared__ float wavemax[4*128];

    const int tid  = threadIdx.x;
    const int lane = tid & 63;
    const int wave = tid >> 6;
    const int n16  = lane & 15;
    const int quad = lane >> 4;

    // ---- XCD-locality swizzle: bid -> (scale, g0) with batch = 2*xcd + hi.
    // Assumes round-robin bid->XCD (bid&7); bijective over 3584 blocks.
    int scale, g0;
    {
        int xcd = blockIdx.x & 7;
        int r   = blockIdx.x >> 3;        // 0..447
        int hi  = (r >= 224) ? 1 : 0;
        int bt  = 2*xcd + hi;             // batch 0..15
        int r2  = r - hi*224;             // 0..223
        if (r2 < 32)       { scale = 0; g0 = bt*256  + r2*GPB; }
        else if (r2 < 96)  { scale = 1; g0 = bt*512  + (r2-32)*GPB; }
        else               { scale = 2; g0 = bt*1024 + (r2-96)*GPB; }
    }
    const int KNB = 16 << scale;
    const int cpg = 4 >> scale;           // centroids per 64-row group
    const int wpc = 1 << scale;           // waves per centroid

    const unsigned short* wt  = wtab + scale * WT_S;
    const unsigned short* w2b = wt + 6144;    // [64][64]
    const unsigned short* w3b = wt + 10240;   // [128][64]

    // ---- resident L1 W fragments: 12 x 16B loads ----
    short8 w1f[4][3];
#pragma unroll
    for (int nt = 0; nt < 4; ++nt)
#pragma unroll
        for (int kb = 0; kb < 3; ++kb)
            w1f[nt][kb] = *(const short8*)&wt[(nt*16 + n16)*96 + kb*32 + quad*8];

    float s1p[4], t1p[4], s2p[4], t2p[4];
    if constexpr (PHASE >= 2) {
#pragma unroll
        for (int nt = 0; nt < 4; ++nt) {
            int o = ((0*3 + scale)*128 + nt*16 + n16)*2;
            s1p[nt] = bnp[o]; t1p[nt] = bnp[o+1];
        }
    }
    if constexpr (PHASE >= 3) {
#pragma unroll
        for (int nt = 0; nt < 4; ++nt) {
            int o = ((1*3 + scale)*128 + nt*16 + n16)*2;
            s2p[nt] = bnp[o]; t2p[nt] = bnp[o+1];
        }
    }

    float sac[8], sqac[8];
#pragma unroll
    for (int i = 0; i < 8; ++i) { sac[i] = 0.f; sqac[i] = 0.f; }
    stat_lds[tid] = 0.f;
    // hoisted zero-pad of g cols 72..95 (gather writes only cols 0..71)
    {
        const int r = tid >> 2;
        const int sub = tid & 3;
        if (sub == 0)      *(uint4*)&g_lds[r*104 + 72] = make_uint4(0u,0u,0u,0u);
        else if (sub == 1) *(uint4*)&g_lds[r*104 + 80] = make_uint4(0u,0u,0u,0u);
        else if (sub == 2) *(uint4*)&g_lds[r*104 + 88] = make_uint4(0u,0u,0u,0u);
    }
    __syncthreads();

    for (int g = g0; g < g0 + GPB; ++g) {
        const int cb = g * cpg;
        // ---- build g tile: 64 rows x 104 cols (bf16) ----
        {
            const int r   = tid >> 2;
            const int sub = tid & 3;
            const int ci  = cb + (r >> (4 + scale));
            const int j   = r & (KNB - 1);
            const int n   = knn[(size_t)ci*64 + j];
            const int b   = ci >> 10;
            if (staged) {
                const unsigned short* frow = featb + ((size_t)(b*NPTS + n))*64 + sub*16;
                uint4 c0 = ((const uint4*)frow)[0];
                uint4 c1 = ((const uint4*)frow)[1];
                *(uint4*)&g_lds[r*104 + sub*16]     = c0;
                *(uint4*)&g_lds[r*104 + sub*16 + 8] = c1;
            } else {
                const float* frow = feat + ((size_t)(b*NPTS + n))*64 + sub*16;
                unsigned short h[16];
#pragma unroll
                for (int u = 0; u < 16; ++u) h[u] = f2bf(frow[u]);
                uint4 p0, p1;
                p0.x = (unsigned)h[0]  | ((unsigned)h[1]  << 16);
                p0.y = (unsigned)h[2]  | ((unsigned)h[3]  << 16);
                p0.z = (unsigned)h[4]  | ((unsigned)h[5]  << 16);
                p0.w = (unsigned)h[6]  | ((unsigned)h[7]  << 16);
                p1.x = (unsigned)h[8]  | ((unsigned)h[9]  << 16);
                p1.y = (unsigned)h[10] | ((unsigned)h[11] << 16);
                p1.z = (unsigned)h[12] | ((unsigned)h[13] << 16);
                p1.w = (unsigned)h[14] | ((unsigned)h[15] << 16);
                *(uint4*)&g_lds[r*104 + sub*16]     = p0;
                *(uint4*)&g_lds[r*104 + sub*16 + 8] = p1;
            }
            if (sub == 0) {
                const float* nx = new_xyz + (size_t)ci*3;
                const float* xp = xyz + ((size_t)(b*NPTS + n))*3;
                unsigned short h0 = f2bf(xp[0] - nx[0]);
                unsigned short h1 = f2bf(xp[1] - nx[1]);
                unsigned short h2 = f2bf(xp[2] - nx[2]);
                uint4 z = make_uint4((unsigned)h0 | ((unsigned)h1 << 16),
                                     (unsigned)h2, 0u, 0u);
                *(uint4*)&g_lds[r*104 + 64] = z;
            }
        }
        __syncthreads();

        // ---- L1 ----
        const int rb = wave*16 + n16;  // A-row for this lane
        short8 a0 = *(const short8*)&g_lds[rb*104 +      quad*8];
        short8 a1 = *(const short8*)&g_lds[rb*104 + 32 + quad*8];
        short8 a2 = *(const short8*)&g_lds[rb*104 + 64 + quad*8];
        floatx4 acc[4];
#pragma unroll
        for (int nt = 0; nt < 4; ++nt) {
            floatx4 c = {0.f,0.f,0.f,0.f};
            c = __builtin_amdgcn_mfma_f32_16x16x32_bf16(a0, w1f[nt][0], c, 0,0,0);
            c = __builtin_amdgcn_mfma_f32_16x16x32_bf16(a1, w1f[nt][1], c, 0,0,0);
            c = __builtin_amdgcn_mfma_f32_16x16x32_bf16(a2, w1f[nt][2], c, 0,0,0);
            acc[nt] = c;
        }

        if constexpr (PHASE == 1) {
#pragma unroll
            for (int nt = 0; nt < 4; ++nt) {
                floatx4 c = acc[nt];
                sac[nt]  += c[0]+c[1]+c[2]+c[3];
                sqac[nt] += c[0]*c[0]+c[1]*c[1]+c[2]*c[2]+c[3]*c[3];
            }
        }
        if constexpr (PHASE >= 2) {
            // a1 = relu(affine(x1)) -> LDS transpose (wave-private slab)
#pragma unroll
            for (int nt = 0; nt < 4; ++nt) {
                int ch = nt*16 + n16;
#pragma unroll
                for (int r = 0; r < 4; ++r) {
                    float v = acc[nt][r]*s1p[nt] + t1p[nt];
                    v = fmaxf(v, 0.f);
                    a_lds[(wave*16 + quad*4 + r)*72 + ch] = f2bf(v);
                }
            }
            short8 e0 = *(const short8*)&a_lds[rb*72 +      quad*8];
            short8 e1 = *(const short8*)&a_lds[rb*72 + 32 + quad*8];
            floatx4 acc2[4];
#pragma unroll
            for (int nt = 0; nt < 4; ++nt) {
                short8 wa = *(const short8*)&w2b[(nt*16 + n16)*64 +      quad*8];
                short8 wb = *(const short8*)&w2b[(nt*16 + n16)*64 + 32 + quad*8];
                floatx4 c = {0.f,0.f,0.f,0.f};
                c = __builtin_amdgcn_mfma_f32_16x16x32_bf16(e0, wa, c, 0,0,0);
                c = __builtin_amdgcn_mfma_f32_16x16x32_bf16(e1, wb, c, 0,0,0);
                acc2[nt] = c;
            }
            if constexpr (PHASE == 2) {
#pragma unroll
                for (int nt = 0; nt < 4; ++nt) {
                    floatx4 c = acc2[nt];
                    sac[nt]  += c[0]+c[1]+c[2]+c[3];
                    sqac[nt] += c[0]*c[0]+c[1]*c[1]+c[2]*c[2]+c[3]*c[3];
                }
            }
            if constexpr (PHASE == 3) {
#pragma unroll
                for (int nt = 0; nt < 4; ++nt) {
                    int ch = nt*16 + n16;
#pragma unroll
                    for (int r = 0; r < 4; ++r) {
                        float v = acc2[nt][r]*s2p[nt] + t2p[nt];
                        v = fmaxf(v, 0.f);
                        a_lds[(wave*16 + quad*4 + r)*72 + ch] = f2bf(v);
                    }
                }
                short8 f0 = *(const short8*)&a_lds[rb*72 +      quad*8];
                short8 f1 = *(const short8*)&a_lds[rb*72 + 32 + quad*8];
#pragma unroll
                for (int nt = 0; nt < 8; ++nt) {
                    short8 wa = *(const short8*)&w3b[(nt*16 + n16)*64 +      quad*8];
                    short8 wb = *(const short8*)&w3b[(nt*16 + n16)*64 + 32 + quad*8];
                    floatx4 c = {0.f,0.f,0.f,0.f};
                    c = __builtin_amdgcn_mfma_f32_16x16x32_bf16(f0, wa, c, 0,0,0);
                    c = __builtin_amdgcn_mfma_f32_16x16x32_bf16(f1, wb, c, 0,0,0);
                    sac[nt]  += c[0]+c[1]+c[2]+c[3];
                    sqac[nt] += c[0]*c[0]+c[1]*c[1]+c[2]*c[2]+c[3]*c[3];
                    float m = fmaxf(fmaxf(c[0],c[1]), fmaxf(c[2],c[3]));
                    m = fmaxf(m, __shfl_xor(m, 16));
                    m = fmaxf(m, __shfl_xor(m, 32));
                    if (lane < 16) wavemax[wave*128 + nt*16 + n16] = m;
                }
            }
        }
        __syncthreads();   // g_lds reuse (all) + cross-wave wavemax (PHASE 3)
        if constexpr (PHASE == 3) {
            const int ch = tid & 127;
            for (int ic = tid >> 7; ic < cpg; ic += 2) {
                float m = wavemax[(ic*wpc)*128 + ch];
                for (int w = 1; w < wpc; ++w)
                    m = fmaxf(m, wavemax[(ic*wpc + w)*128 + ch]);
                // raw (pre-BN3) max, f32, directly in the final output slot
                out1[(size_t)(cb + ic)*384 + scale*128 + ch] = m;
            }
        }
    }

    // ---- flush stats ----
    const int NCH = (PHASE == 3) ? 8 : 4;
#pragma unroll
    for (int nt = 0; nt < 8; ++nt) {
        if (nt >= NCH) break;
        float v  = sac[nt], v2 = sqac[nt];
        v  += __shfl_xor(v, 16);  v  += __shfl_xor(v, 32);
        v2 += __shfl_xor(v2, 16); v2 += __shfl_xor(v2, 32);
        if (lane < 16) {
            int ch = nt*16 + n16;
            atomicAdd(&stat_lds[ch*2],   v);
            atomicAdd(&stat_lds[ch*2+1], v2);
        }
    }
    __syncthreads();
    const int layer = PHASE - 1;
    const int nch = (PHASE == 3) ? 128 : 64;
    if (tid < nch*2) {
        atomicAdd(&stats[(size_t)(layer*3 + scale)*256 + tid], stat_lds[tid]);
    }
}

// ---------------------------------------------------------------------------
__global__ void bn_params_kernel(
    const float* __restrict__ stats, float* __restrict__ bnp,
    const float* __restrict__ gamma, const float* __restrict__ beta,
    int layer, int nch)
{
    int t = blockIdx.x * blockDim.x + threadIdx.x;
    if (t >= 3*nch) return;
    int scale = t / nch, ch = t % nch;
    float M = 16384.0f * (float)(16 << scale);
    int o = ((layer*3 + scale)*128 + ch)*2;
    float sum = stats[o], sumsq = stats[o+1];
    float mean = sum / M;
    float var = sumsq / M - mean*mean;
    var = fmaxf(var, 0.f);
    float ga = gamma[scale*nch + ch];
    float be = beta[scale*nch + ch];
    float s  = ga / sqrtf(var + 1e-5f);
    float tt = be - mean * s;
    bnp[o] = s; bnp[o+1] = tt;
}

// In-place elementwise BN3+ReLU over the fused output region (f32, float4).
// 4-aligned channel groups never straddle the scale boundary (128%4==0).
__global__ void finalize_kernel(
    const float* __restrict__ bnp,
    float* __restrict__ out1)   // [B*S, 384] f32, holds raw maxima
{
    int t = blockIdx.x * 256 + threadIdx.x;    // 1,572,864 float4 groups
    float4 m = ((const float4*)out1)[t];
    int c0 = (t*4) % 384;
    int scale = c0 >> 7;
    int ch = c0 & 127;
    int o = ((2*3 + scale)*128 + ch)*2;
    float4 r;
    r.x = fmaxf(m.x*bnp[o+0] + bnp[o+1], 0.f);
    r.y = fmaxf(m.y*bnp[o+2] + bnp[o+3], 0.f);
    r.z = fmaxf(m.z*bnp[o+4] + bnp[o+5], 0.f);
    r.w = fmaxf(m.w*bnp[o+6] + bnp[o+7], 0.f);
    ((float4*)out1)[t] = r;
}

// ---------------------------------------------------------------------------
extern "C" void kernel_launch(void* const* d_in, const int* in_sizes, int n_in,
                              void* d_out, int out_size, void* d_ws, size_t ws_size,
                              hipStream_t stream)
{
    (void)in_sizes; (void)n_in; (void)out_size;
    const float* xyz  = (const float*)d_in[0];
    const float* feat = (const float*)d_in[1];
    const float* w0   = (const float*)d_in[2];
    const float* w1   = (const float*)d_in[3];
    const float* w2   = (const float*)d_in[4];
    const float* g0   = (const float*)d_in[5];
    const float* g1   = (const float*)d_in[6];
    const float* g2   = (const float*)d_in[7];
    const float* b0   = (const float*)d_in[8];
    const float* b1   = (const float*)d_in[9];
    const float* b2   = (const float*)d_in[10];
    float* out  = (float*)d_out;
    float* out0 = out;                 // [B,S,3]
    float* out1 = out + 49152;         // fused [B*S,384]

    // ws layouts:
    //  staged:   knn 2MB | featb 8MB | stats 9216 | bnp 9216 | wtab 110592
    //  fallback: knn 2MB | stats 9216 | bnp 9216 | wtab 110592
    char* ws = (char*)d_ws;
    const size_t NEED_FULL = 2097152ull + 8388608ull + 9216 + 9216 + 110592;
    const int staged = (ws_size >= NEED_FULL) ? 1 : 0;
    unsigned short* knn   = (unsigned short*)ws;
    unsigned short* featb = staged ? (unsigned short*)(ws + 2097152) : nullptr;
    size_t tail = staged ? (2097152ull + 8388608ull) : 2097152ull;
    float* stats = (float*)(ws + tail);
    float* bnp   = (float*)(ws + tail + 9216);
    unsigned short* wtab = (unsigned short*)(ws + tail + 18432);

    hipMemsetAsync(stats, 0, 9216, stream);
    // fps (blocks 0-15) + feat->bf16 (1024 blocks, staged) + wtab (108 blocks)
    fps_conv_kernel<<<16 + (staged ? 1024 : 0) + 108, 512, 0, stream>>>(
        xyz, out0, feat, featb, staged, w0, w1, w2, wtab);
    knn_kernel<<<1024, 1024, 0, stream>>>(xyz, out0, knn);

    mlp_phase<1><<<3584,256,0,stream>>>(xyz,feat,out0,knn,featb,staged,wtab,bnp,stats,out1);
    bn_params_kernel<<<1,256,0,stream>>>(stats, bnp, g0, b0, 0, 64);

    mlp_phase<2><<<3584,256,0,stream>>>(xyz,feat,out0,knn,featb,staged,wtab,bnp,stats,out1);
    bn_params_kernel<<<1,256,0,stream>>>(stats, bnp, g1, b1, 1, 64);

    mlp_phase<3><<<3584,256,0,stream>>>(xyz,feat,out0,knn,featb,staged,wtab,bnp,stats,out1);
    bn_params_kernel<<<2,256,0,stream>>>(stats, bnp, g2, b2, 2, 128);

    finalize_kernel<<<6144, 256, 0, stream>>>(bnp, out1);
}